// Round 6
// baseline (173.629 us; speedup 1.0000x reference)
//
#include <hip/hip_runtime.h>
#include <hip/hip_bf16.h>

// ColorHistogramLoss — wave-split soft histogram: 16 named scalar
// accumulators per lane (bins split across 4 lane-quarters).
//
// Post-mortem history:
//  R2/R5: acc[64] register array + variable-index butterfly -> SROA fails
//    (variable GEPs before unroll) -> acc lives in SCRATCH all kernel ->
//    L2-BW-bound on spill traffic (~1.6 GB) -> 66-73 us, VALUBusy 11-14%,
//    VGPR_Count 48-64 (too small to hold acc — the tell).
//  R3: divergent LDS atomics ~245 cyc/instr -> 118 us.
//  R4: 32KB private LDS columns -> 2 waves/SIMD, ds-latency-bound -> 78 us.
// Fix: NO arrays at all. Lane (q=lane>>4, s=lane&15) owns bins [16q,16q+16)
// as 16 named floats. Per 64-px batch: 1 coalesced load + 4 shfl broadcasts;
// each lane evals its two 8-bin power-form segments per pixel:
//   w_k = w0 * m^k * e^{-k(k-1)/2}, w0=e^{-u^2/2}, m=e^{min(u,13)-0.5}
// (clamp keeps m^7 finite; far-tail w0 underflows to 0 -> 0*finite, exact
// same math as R2/R5 which passed with absmax 0.0).
// Reduce: 4 shfl_xor levels within 16-lane groups (named, constant),
// 4 lanes/wave -> 16 LDS atomics (distinct addrs), block -> global atomic;
// last-arriving block (agent-scope ACQ_REL counter) runs scan/cdf/mean tail.

#define BINS 64
#define NCH 12            // B*C
#define HW 65536          // 256*256
#define THREADS 256
#define PXB 1024                             // pixels per block
#define BPC (HW / PXB)                       // 64 blocks per channel-image
#define NBLK (2 * NCH * BPC)                 // 1536 (= 6 blocks/CU exactly)
#define BATCHES 4                            // 4 x 64-px batches per wave

// K_k = e^{-k(k-1)/2}
#define K2 0.36787944117144233f
#define K3 0.049787068367863944f
#define K4 0.0024787521766663585f
#define K5 4.5399929762484854e-05f
#define K6 3.059023205018258e-07f
#define K7 7.582560427911907e-10f
#define LOG2E   1.4426950408889634f
#define LOG2E_H 0.7213475204444817f

__device__ __forceinline__ float fast_exp2(float x) {
#if __has_builtin(__builtin_amdgcn_exp2f)
    return __builtin_amdgcn_exp2f(x);
#else
    return exp2f(x);
#endif
}

// one 8-bin segment: base distance U, named accumulators A0..A7
#define SEG(U, A0,A1,A2,A3,A4,A5,A6,A7) do {                         \
    float u_  = (U);                                                 \
    float um_ = fminf(u_, 13.0f);                                    \
    float w0_ = fast_exp2(-(u_ * u_) * LOG2E_H);                     \
    float m_  = fast_exp2(fmaf(um_, LOG2E, -0.5f * LOG2E));          \
    float m2_ = m_ * m_,  m3_ = m2_ * m_,  m4_ = m2_ * m2_;          \
    float m5_ = m3_ * m2_, m6_ = m3_ * m3_, m7_ = m4_ * m3_;         \
    A0 += w0_;                                                       \
    A1 = fmaf(w0_,      m_,  A1);                                    \
    A2 = fmaf(w0_ * K2, m2_, A2);                                    \
    A3 = fmaf(w0_ * K3, m3_, A3);                                    \
    A4 = fmaf(w0_ * K4, m4_, A4);                                    \
    A5 = fmaf(w0_ * K5, m5_, A5);                                    \
    A6 = fmaf(w0_ * K6, m6_, A6);                                    \
    A7 = fmaf(w0_ * K7, m7_, A7);                                    \
} while (0)

#define EVALPX(T) do {                                               \
    SEG((T) - qb - 0.5f, a0,a1,a2,a3,a4,a5,a6,a7);                   \
    SEG((T) - qb - 8.5f, a8,a9,a10,a11,a12,a13,a14,a15);             \
} while (0)

#define RED(X) do {                                                  \
    X += __shfl_xor(X, 1, 64); X += __shfl_xor(X, 2, 64);            \
    X += __shfl_xor(X, 4, 64); X += __shfl_xor(X, 8, 64);            \
} while (0)

__global__ __launch_bounds__(THREADS, 4) void fused_kernel(
        const float* __restrict__ pred,
        const float* __restrict__ target,
        float* __restrict__ hist,           // ws: 24*64 floats, pre-zeroed
        unsigned int* __restrict__ counter, // ws: 1 uint, pre-zeroed
        float* __restrict__ out) {
    const int tid   = threadIdx.x;
    const int blk   = blockIdx.x;
    const int ch    = blk / BPC;            // 0..23
    const int chunk = blk % BPC;
    const int lane  = tid & 63;
    const int wv    = tid >> 6;             // wave 0..3
    const int q     = lane >> 4;            // bin quarter
    const int s     = lane & 15;            // slot within quarter
    const float qb  = (float)(q * 16);      // quarter's bin base

    const float* src = (ch < NCH) ? (pred + (size_t)ch * HW)
                                  : (target + (size_t)(ch - NCH) * HW);
    const float* wsrc = src + (size_t)chunk * PXB + wv * (BATCHES * 64);

    float a0 = 0.f, a1 = 0.f, a2 = 0.f, a3 = 0.f;
    float a4 = 0.f, a5 = 0.f, a6 = 0.f, a7 = 0.f;
    float a8 = 0.f, a9 = 0.f, a10 = 0.f, a11 = 0.f;
    float a12 = 0.f, a13 = 0.f, a14 = 0.f, a15 = 0.f;

    #pragma unroll
    for (int b = 0; b < BATCHES; ++b) {
        float t  = wsrc[b * 64 + lane] * 64.0f;   // coalesced, 1 px/lane
        float t0 = __shfl(t, s,      64);          // broadcast to all quarters
        float t1 = __shfl(t, s + 16, 64);
        float t2 = __shfl(t, s + 32, 64);
        float t3 = __shfl(t, s + 48, 64);
        EVALPX(t0); EVALPX(t1); EVALPX(t2); EVALPX(t3);
    }

    // reduce across the 16 slots of each quarter (xor masks stay in-group)
    RED(a0);  RED(a1);  RED(a2);  RED(a3);
    RED(a4);  RED(a5);  RED(a6);  RED(a7);
    RED(a8);  RED(a9);  RED(a10); RED(a11);
    RED(a12); RED(a13); RED(a14); RED(a15);

    __shared__ float bh[BINS];
    __shared__ int is_last;
    if (tid < BINS) bh[tid] = 0.0f;
    __syncthreads();
    if (s == 0) {                            // 4 lanes/wave, distinct addrs
        float* dst = bh + q * 16;
        atomicAdd(dst + 0,  a0);  atomicAdd(dst + 1,  a1);
        atomicAdd(dst + 2,  a2);  atomicAdd(dst + 3,  a3);
        atomicAdd(dst + 4,  a4);  atomicAdd(dst + 5,  a5);
        atomicAdd(dst + 6,  a6);  atomicAdd(dst + 7,  a7);
        atomicAdd(dst + 8,  a8);  atomicAdd(dst + 9,  a9);
        atomicAdd(dst + 10, a10); atomicAdd(dst + 11, a11);
        atomicAdd(dst + 12, a12); atomicAdd(dst + 13, a13);
        atomicAdd(dst + 14, a14); atomicAdd(dst + 15, a15);
    }
    __syncthreads();
    if (tid < BINS)
        atomicAdd(&hist[ch * BINS + tid], bh[tid]);

    // block-completion counter (release our atomics, acquire others')
    __threadfence();
    if (tid == 0) {
        unsigned prev = __hip_atomic_fetch_add(counter, 1u, __ATOMIC_ACQ_REL,
                                               __HIP_MEMORY_SCOPE_AGENT);
        is_last = (prev == NBLK - 1);
    }
    __syncthreads();
    if (!is_last) return;

    // ---- tail: scan/cdf/|diff|/mean, this block (4 waves) ----
    float local = 0.0f;
    for (int pch = wv; pch < NCH; pch += 4) {
        float ps = hist[pch * BINS + lane];
        float ts = hist[(NCH + pch) * BINS + lane];
        #pragma unroll
        for (int d = 1; d < 64; d <<= 1) {
            float aa = __shfl_up(ps, d, 64);
            float bb = __shfl_up(ts, d, 64);
            if (lane >= d) { ps += aa; ts += bb; }
        }
        float ptot = __shfl(ps, 63, 64);
        float ttot = __shfl(ts, 63, 64);
        float dv = fabsf(ps / (ptot + 1e-8f) - ts / (ttot + 1e-8f));
        #pragma unroll
        for (int k = 32; k >= 1; k >>= 1) dv += __shfl_xor(dv, k, 64);
        local += dv;
    }
    __shared__ float wsum[4];
    if (lane == 0) wsum[wv] = local;
    __syncthreads();
    if (tid == 0)
        out[0] = (wsum[0] + wsum[1] + wsum[2] + wsum[3]) * (1.0f / (NCH * BINS));
}

extern "C" void kernel_launch(void* const* d_in, const int* in_sizes, int n_in,
                              void* d_out, int out_size, void* d_ws, size_t ws_size,
                              hipStream_t stream) {
    const float* pred   = (const float*)d_in[0];
    const float* target = (const float*)d_in[1];
    float* hist = (float*)d_ws;                      // 24*64 floats
    unsigned int* counter = (unsigned int*)((char*)d_ws + NCH * 2 * BINS * 4);
    float* out = (float*)d_out;

    hipMemsetAsync(d_ws, 0, NCH * 2 * BINS * 4 + 4, stream);
    fused_kernel<<<dim3(NBLK), dim3(THREADS), 0, stream>>>(
        pred, target, hist, counter, out);
}